// Round 1
// baseline (3813.184 us; speedup 1.0000x reference)
//
#include <hip/hip_runtime.h>
#include <hip/hip_bf16.h>

// Problem: B=16, C=64 in/out, H=W=96, 3x3 convs, AK=3 attention kernels.
// Pipeline: kf=conv(x1,w1); qf=conv(x2,w2); scores[b,d,c*9+k] over strided
// pixel classes; softmax(576); vf=conv(x1,w3); out = dynamic 3x3x64 conv of vf
// with per-(b,d) kernels attn.

#define HW96 96
#define PLANE (96*96)
constexpr int CH = 64;
constexpr int PLANE_F = 9437184;   // B*C*H*W floats
constexpr int SC_F = 589824;       // B*64*576 floats

// ---------------- conv 3x3 (static weights OR per-batch dynamic rows) -------
// grid: B * 32 * 3  (b, cout-pair, 32-col strip). block 192 = 8 colgroups x 24 rowgroups
__global__ __launch_bounds__(192) void conv3x3_kernel(
    const float* __restrict__ x, const float* __restrict__ wrows,
    float* __restrict__ out, int wPerBatch)
{
    int blk = blockIdx.x;
    int cs  = blk % 3;
    int t   = blk / 3;
    int cop = t & 31;
    int b   = t >> 5;
    int co0 = cop * 2;
    int x0c = cs * 32;

    __shared__ __align__(16) float xs[98][36];   // rows -1..96, cols x0c-1..x0c+32
    __shared__ float wl[2][576];

    int wbase = (wPerBatch ? b * 64 : 0) + co0;
    for (int i = threadIdx.x; i < 1152; i += 192) {
        int u = i / 576; int r = i - u * 576;
        wl[u][r] = wrows[(size_t)(wbase + u) * 576 + r];
    }

    int cg = threadIdx.x & 7;    // 0..7 -> 4 cols each
    int rg = threadIdx.x >> 3;   // 0..23 -> 4 rows each
    int xloc = cg * 4;

    float acc[2][4][4] = {};

    const float* xb = x + (size_t)b * CH * PLANE;

    for (int ci = 0; ci < CH; ++ci) {
        __syncthreads();
        const float* xp = xb + (size_t)ci * PLANE;
        for (int i = threadIdx.x; i < 98 * 34; i += 192) {
            int r = i / 34, c = i - r * 34;
            int y = r - 1, xcol = x0c + c - 1;
            float v = 0.f;
            if ((unsigned)y < 96u && (unsigned)xcol < 96u) v = xp[y * 96 + xcol];
            xs[r][c] = v;
        }
        __syncthreads();

        float w0[9], w1[9];
        #pragma unroll
        for (int t2 = 0; t2 < 9; ++t2) { w0[t2] = wl[0][ci*9+t2]; w1[t2] = wl[1][ci*9+t2]; }

        float win[6][6];
        #pragma unroll
        for (int r = 0; r < 6; ++r) {
            int lr = rg * 4 + r;
            float4 a4 = *(const float4*)&xs[lr][xloc];
            float2 a2 = *(const float2*)&xs[lr][xloc + 4];
            win[r][0]=a4.x; win[r][1]=a4.y; win[r][2]=a4.z; win[r][3]=a4.w;
            win[r][4]=a2.x; win[r][5]=a2.y;
        }
        #pragma unroll
        for (int j = 0; j < 4; ++j) {
            #pragma unroll
            for (int i2 = 0; i2 < 4; ++i2) {
                float s0 = acc[0][j][i2], s1 = acc[1][j][i2];
                #pragma unroll
                for (int dy = 0; dy < 3; ++dy) {
                    #pragma unroll
                    for (int dx = 0; dx < 3; ++dx) {
                        float xv = win[j + dy][i2 + dx];
                        s0 += w0[dy*3+dx] * xv;
                        s1 += w1[dy*3+dx] * xv;
                    }
                }
                acc[0][j][i2] = s0; acc[1][j][i2] = s1;
            }
        }
    }

    #pragma unroll
    for (int u = 0; u < 2; ++u) {
        float* op = out + (size_t)(b * 64 + co0 + u) * PLANE;
        #pragma unroll
        for (int j = 0; j < 4; ++j) {
            int Y = rg * 4 + j;
            float4 v;
            v.x = acc[u][j][0]; v.y = acc[u][j][1];
            v.z = acc[u][j][2]; v.w = acc[u][j][3];
            *(float4*)&op[Y * 96 + x0c + xloc] = v;
        }
    }
}

// ---------------- scores: per (b,k,seg) 64x64 GEMM over L-subset ------------
// scores[b,k,c,d] = sum_{y%3==kh, x%3==kw} kf[b,c,y,x]*qf[b,d,y,x]
// write raw partials (scaled later) at scp[seg][b*64+d][c*9+k]
__global__ __launch_bounds__(256) void scores_kernel(
    const float* __restrict__ kf, const float* __restrict__ qf,
    float* __restrict__ scp, int nseg)
{
    int blk = blockIdx.x;
    int seg = blk % nseg;
    int bk  = blk / nseg;
    int b = bk / 9, k = bk - b * 9;
    int kh = k / 3, kw = k - kh * 3;

    __shared__ __align__(16) float Kt[64][68];
    __shared__ __align__(16) float Qt[64][68];

    const float* kb = kf + (size_t)b * 64 * PLANE;
    const float* qb = qf + (size_t)b * 64 * PLANE;
    int tc = threadIdx.x >> 4, td = threadIdx.x & 15;

    float acc[4][4] = {};
    int lcnt = 1024 / nseg;
    int lstart = seg * lcnt;
    for (int l0 = lstart; l0 < lstart + lcnt; l0 += 64) {
        __syncthreads();
        for (int i = threadIdx.x; i < 4096; i += 256) {
            int ch = i >> 6, ll = i & 63;
            int l = l0 + ll;
            int py = l >> 5, px = l & 31;
            int y = 3 * py + kh, xx = 3 * px + kw;
            Kt[ch][ll] = kb[(size_t)ch * PLANE + y * 96 + xx];
            Qt[ch][ll] = qb[(size_t)ch * PLANE + y * 96 + xx];
        }
        __syncthreads();
        #pragma unroll 4
        for (int ll = 0; ll < 64; ll += 4) {
            float4 kv[4], qv[4];
            #pragma unroll
            for (int i = 0; i < 4; ++i) kv[i] = *(const float4*)&Kt[tc*4+i][ll];
            #pragma unroll
            for (int j = 0; j < 4; ++j) qv[j] = *(const float4*)&Qt[td*4+j][ll];
            #pragma unroll
            for (int i = 0; i < 4; ++i)
                #pragma unroll
                for (int j = 0; j < 4; ++j)
                    acc[i][j] += kv[i].x*qv[j].x + kv[i].y*qv[j].y
                               + kv[i].z*qv[j].z + kv[i].w*qv[j].w;
        }
    }
    #pragma unroll
    for (int i = 0; i < 4; ++i)
        #pragma unroll
        for (int j = 0; j < 4; ++j) {
            int c = tc * 4 + i, d = td * 4 + j;
            scp[(size_t)seg * SC_F + (size_t)(b * 64 + d) * 576 + c * 9 + k] = acc[i][j];
        }
}

// ---------------- softmax over 576, one wave per row ------------------------
__global__ __launch_bounds__(64) void softmax_kernel(float* __restrict__ sc, int nseg)
{
    int row = blockIdx.x;            // b*64+d, 0..1023
    int lane = threadIdx.x;
    size_t base = (size_t)row * 576 + lane;
    float v[9];
    float mx = -3.0e38f;
    #pragma unroll
    for (int i = 0; i < 9; ++i) {
        float s = sc[base + i * 64];
        for (int g = 1; g < nseg; ++g) s += sc[(size_t)g * SC_F + base + i * 64];
        v[i] = s * (1.0f / 24.0f);   // 1/sqrt(576)
        mx = fmaxf(mx, v[i]);
    }
    #pragma unroll
    for (int o = 32; o; o >>= 1) mx = fmaxf(mx, __shfl_down(mx, o));
    mx = __shfl(mx, 0);
    float sum = 0.f;
    #pragma unroll
    for (int i = 0; i < 9; ++i) { v[i] = __expf(v[i] - mx); sum += v[i]; }
    #pragma unroll
    for (int o = 32; o; o >>= 1) sum += __shfl_down(sum, o);
    sum = __shfl(sum, 0);
    float inv = 1.0f / sum;
    #pragma unroll
    for (int i = 0; i < 9; ++i) sc[base + i * 64] = v[i] * inv;
}

extern "C" void kernel_launch(void* const* d_in, const int* in_sizes, int n_in,
                              void* d_out, int out_size, void* d_ws, size_t ws_size,
                              hipStream_t stream) {
    (void)in_sizes; (void)n_in; (void)out_size;
    const float* x1 = (const float*)d_in[0];
    const float* x2 = (const float*)d_in[1];
    const float* w1 = (const float*)d_in[2];
    const float* w2 = (const float*)d_in[3];
    const float* w3 = (const float*)d_in[4];
    float* out = (float*)d_out;

    float* kf = (float*)d_ws;            // also reused for vf later
    float* qf = kf + PLANE_F;
    float* sc = qf + PLANE_F;            // final attn lives in segment 0

    // 4 L-segments of partial scores if workspace allows, else 1
    int nseg = (ws_size >= (size_t)(2 * PLANE_F + 4 * SC_F) * 4) ? 4 : 1;

    dim3 cblk(192), cgrid(1536);
    conv3x3_kernel<<<cgrid, cblk, 0, stream>>>(x1, w1, kf, 0);
    conv3x3_kernel<<<cgrid, cblk, 0, stream>>>(x2, w2, qf, 0);
    scores_kernel<<<dim3(144 * nseg), dim3(256), 0, stream>>>(kf, qf, sc, nseg);
    softmax_kernel<<<dim3(1024), dim3(64), 0, stream>>>(sc, nseg);
    conv3x3_kernel<<<cgrid, cblk, 0, stream>>>(x1, w3, kf, 0);        // vf
    conv3x3_kernel<<<cgrid, cblk, 0, stream>>>(kf, sc, out, 1);       // dynamic conv
}

// Round 2
// 287.843 us; speedup vs baseline: 13.2475x; 13.2475x over previous
//
#include <hip/hip_runtime.h>

// B=16, C=64->64, H=W=96, 3x3 pad-1 convs + 9-tap dynamic conv from attention.
// All convs = bf16 MFMA implicit GEMM: M=64 cout, K=576 (9 taps x 64 ci), N=pixels.

typedef __attribute__((ext_vector_type(8))) short short8v;   // 8 bf16 = 4 VGPRs
typedef __attribute__((ext_vector_type(4))) float floatx4;
typedef __attribute__((ext_vector_type(4))) unsigned int uint4v;

constexpr int PLANE = 9216;            // 96*96
constexpr int SC_F = 589824;           // B*64*576 floats

__device__ __forceinline__ unsigned short f2bf(float f) {
    unsigned int u = __float_as_uint(f);
    u = (u + 0x7FFFu + ((u >> 16) & 1u)) >> 16;
    return (unsigned short)u;
}
__device__ __forceinline__ float bf2f(unsigned short h) {
    return __uint_as_float(((unsigned int)h) << 16);
}

// ---------- fp32 NCHW -> bf16 NHWC (channels contiguous per pixel) ----------
// grid: B*96 (one block per (b,y) row), block 256
__global__ __launch_bounds__(256) void nchw2nhwc_bf16(
    const float* __restrict__ x, unsigned short* __restrict__ xh)
{
    int blk = blockIdx.x;
    int b = blk / 96, y = blk - b * 96;
    __shared__ float ls[64][96];
    const float* xp = x + (size_t)b * 64 * PLANE + (size_t)y * 96;
    for (int i = threadIdx.x; i < 64 * 96; i += 256) {
        int ci = i / 96, xc = i - ci * 96;
        ls[ci][xc] = xp[(size_t)ci * PLANE + xc];
    }
    __syncthreads();
    unsigned short* op = xh + ((size_t)b * PLANE + (size_t)y * 96) * 64;
    for (int i = threadIdx.x; i < 96 * 8; i += 256) {
        int xc = i >> 3, cg = i & 7;
        unsigned short tmp[8] __attribute__((aligned(16)));
        #pragma unroll
        for (int j = 0; j < 8; ++j) tmp[j] = f2bf(ls[cg * 8 + j][xc]);
        *(uint4v*)&op[(size_t)xc * 64 + cg * 8] = *(const uint4v*)tmp;
    }
}

// ---------- weights [co][ci][kh][kw] fp32 -> [tap][co][ci] bf16 -------------
// grid 27 = 3 weights x 9 taps
__global__ __launch_bounds__(256) void wreorder(
    const float* __restrict__ w1, const float* __restrict__ w2,
    const float* __restrict__ w3, unsigned short* __restrict__ wl)
{
    int blk = blockIdx.x;
    int wi = blk / 9, k9 = blk - wi * 9;
    const float* w = (wi == 0) ? w1 : ((wi == 1) ? w2 : w3);
    unsigned short* o = wl + (size_t)wi * 9 * 4096 + (size_t)k9 * 4096;
    for (int i = threadIdx.x; i < 4096; i += 256)   // i = co*64+ci
        o[i] = f2bf(w[(size_t)i * 9 + k9]);
}

// ---------- MFMA conv: 64 cout x 128 px (32w x 4h) per block ----------------
// omode: 0 = bf16 NCHW out, 1 = bf16 NHWC out, 2 = fp32 NCHW out
// dynb: weights are per-batch (dynamic conv)
// grid: B*24*3 = 1152, block 256 (4 waves; wave w -> couts [16w,16w+16))
__global__ __launch_bounds__(256) void conv_mfma(
    const unsigned short* __restrict__ xh,   // [B][96][96][64] bf16
    const unsigned short* __restrict__ wl,   // [(b)][9][64co][64ci] bf16
    void* __restrict__ out, int omode, int dynb)
{
    int blk = blockIdx.x;
    int xs3 = blk % 3; int t = blk / 3;
    int yq = t % 24;   int b = t / 24;
    int x0 = xs3 * 32, y0 = yq * 4;

    __shared__ __align__(16) unsigned short xs[6][34][72];  // +8 pad spreads banks

    const unsigned short* xb = xh + (size_t)b * PLANE * 64;
    for (int i = threadIdx.x; i < 6 * 34 * 8; i += 256) {
        int cg = i & 7, pix = i >> 3;
        int pr = pix / 34, pc = pix - pr * 34;
        int y = y0 - 1 + pr, x = x0 - 1 + pc;
        uint4v v = {0u, 0u, 0u, 0u};
        if ((unsigned)y < 96u && (unsigned)x < 96u)
            v = *(const uint4v*)&xb[((size_t)y * 96 + x) * 64 + cg * 8];
        *(uint4v*)&xs[pr][pc][cg * 8] = v;
    }
    __syncthreads();

    int lane = threadIdx.x & 63;
    int w = threadIdx.x >> 6;
    int ln = lane & 15, quad = lane >> 4;

    const unsigned short* wb = wl + (dynb ? (size_t)b * 9 * 4096 : 0);

    floatx4 acc[8];
    #pragma unroll
    for (int i = 0; i < 8; ++i) acc[i] = (floatx4){0.f, 0.f, 0.f, 0.f};

    #pragma unroll
    for (int k9 = 0; k9 < 9; ++k9) {
        int dy = k9 / 3, dx = k9 - dy * 3;
        #pragma unroll
        for (int ch = 0; ch < 2; ++ch) {
            // A[m=ln][k=quad*8+j] : weights, 8 consecutive ci
            short8v a = *(const short8v*)
                &wb[((size_t)k9 * 64 + (w * 16 + ln)) * 64 + ch * 32 + quad * 8];
            #pragma unroll
            for (int nt = 0; nt < 8; ++nt) {
                int n = nt * 16 + ln;
                int r = n >> 5, c = n & 31;
                // B[k=quad*8+j][n=ln] : shifted pixel, 8 consecutive ci
                short8v bf = *(const short8v*)
                    &xs[r + dy][c + dx][ch * 32 + quad * 8];
                acc[nt] = __builtin_amdgcn_mfma_f32_16x16x32_bf16(a, bf, acc[nt], 0, 0, 0);
            }
        }
    }

    // C/D: col(pixel)=lane&15, row(cout)=quad*4+reg
    #pragma unroll
    for (int nt = 0; nt < 8; ++nt) {
        int n = nt * 16 + ln;
        int r = n >> 5, c = n & 31;
        int y = y0 + r, x = x0 + c;
        if (omode == 2) {
            float* o = (float*)out;
            #pragma unroll
            for (int reg = 0; reg < 4; ++reg) {
                int co = w * 16 + quad * 4 + reg;
                o[((size_t)(b * 64 + co)) * PLANE + (size_t)y * 96 + x] = acc[nt][reg];
            }
        } else if (omode == 0) {
            unsigned short* o = (unsigned short*)out;
            #pragma unroll
            for (int reg = 0; reg < 4; ++reg) {
                int co = w * 16 + quad * 4 + reg;
                o[((size_t)(b * 64 + co)) * PLANE + (size_t)y * 96 + x] = f2bf(acc[nt][reg]);
            }
        } else {
            unsigned short* o = (unsigned short*)out;
            unsigned short tmp[4] __attribute__((aligned(8)));
            #pragma unroll
            for (int reg = 0; reg < 4; ++reg) tmp[reg] = f2bf(acc[nt][reg]);
            *(uint2*)&o[((size_t)b * PLANE + (size_t)y * 96 + x) * 64 + w * 16 + quad * 4]
                = *(const uint2*)tmp;
        }
    }
}

// ---------- scores: per (b,tap,seg) 64x64 GEMM over strided pixel class ----
__global__ __launch_bounds__(256) void scores_kernel(
    const unsigned short* __restrict__ kf, const unsigned short* __restrict__ qf,
    float* __restrict__ scp, int nseg)
{
    int blk = blockIdx.x;
    int seg = blk % nseg;
    int bk  = blk / nseg;
    int b = bk / 9, k = bk - b * 9;
    int kh = k / 3, kw = k - kh * 3;

    __shared__ __align__(16) float Kt[64][68];
    __shared__ __align__(16) float Qt[64][68];

    const unsigned short* kb = kf + (size_t)b * 64 * PLANE;
    const unsigned short* qb = qf + (size_t)b * 64 * PLANE;
    int tc = threadIdx.x >> 4, td = threadIdx.x & 15;

    float acc[4][4] = {};
    int lcnt = 1024 / nseg;
    int lstart = seg * lcnt;
    for (int l0 = lstart; l0 < lstart + lcnt; l0 += 64) {
        __syncthreads();
        for (int i = threadIdx.x; i < 4096; i += 256) {
            int ch = i >> 6, ll = i & 63;
            int l = l0 + ll;
            int py = l >> 5, px = l & 31;
            int y = 3 * py + kh, xx = 3 * px + kw;
            Kt[ch][ll] = bf2f(kb[(size_t)ch * PLANE + y * 96 + xx]);
            Qt[ch][ll] = bf2f(qb[(size_t)ch * PLANE + y * 96 + xx]);
        }
        __syncthreads();
        #pragma unroll 4
        for (int ll = 0; ll < 64; ll += 4) {
            float4 kv[4], qv[4];
            #pragma unroll
            for (int i = 0; i < 4; ++i) kv[i] = *(const float4*)&Kt[tc * 4 + i][ll];
            #pragma unroll
            for (int j = 0; j < 4; ++j) qv[j] = *(const float4*)&Qt[td * 4 + j][ll];
            #pragma unroll
            for (int i = 0; i < 4; ++i)
                #pragma unroll
                for (int j = 0; j < 4; ++j)
                    acc[i][j] += kv[i].x * qv[j].x + kv[i].y * qv[j].y
                               + kv[i].z * qv[j].z + kv[i].w * qv[j].w;
        }
    }
    #pragma unroll
    for (int i = 0; i < 4; ++i)
        #pragma unroll
        for (int j = 0; j < 4; ++j) {
            int c = tc * 4 + i, d = td * 4 + j;
            scp[(size_t)seg * SC_F + (size_t)(b * 64 + d) * 576 + c * 9 + k] = acc[i][j];
        }
}

// ---------- softmax over 576 -> dynamic conv weights [b][tap][d][c] bf16 ----
__global__ __launch_bounds__(64) void softmax_kernel(
    const float* __restrict__ sc, unsigned short* __restrict__ dynw, int nseg)
{
    int row = blockIdx.x;            // b*64+d
    int lane = threadIdx.x;
    size_t base = (size_t)row * 576 + lane;
    float v[9];
    float mx = -3.0e38f;
    #pragma unroll
    for (int i = 0; i < 9; ++i) {
        float s = sc[base + i * 64];
        for (int g = 1; g < nseg; ++g) s += sc[(size_t)g * SC_F + base + i * 64];
        v[i] = s * (1.0f / 24.0f);   // 1/sqrt(576)
        mx = fmaxf(mx, v[i]);
    }
    #pragma unroll
    for (int o = 32; o; o >>= 1) mx = fmaxf(mx, __shfl_down(mx, o));
    mx = __shfl(mx, 0);
    float sum = 0.f;
    #pragma unroll
    for (int i = 0; i < 9; ++i) { v[i] = __expf(v[i] - mx); sum += v[i]; }
    #pragma unroll
    for (int o = 32; o; o >>= 1) sum += __shfl_down(sum, o);
    sum = __shfl(sum, 0);
    float inv = 1.0f / sum;
    int b = row >> 6, d = row & 63;
    #pragma unroll
    for (int i = 0; i < 9; ++i) {
        int e = i * 64 + lane;       // e = c*9 + k
        int c = e / 9, k = e - c * 9;
        dynw[(((size_t)b * 9 + k) * 64 + d) * 64 + c] = f2bf(v[i] * inv);
    }
}

extern "C" void kernel_launch(void* const* d_in, const int* in_sizes, int n_in,
                              void* d_out, int out_size, void* d_ws, size_t ws_size,
                              hipStream_t stream) {
    (void)in_sizes; (void)n_in; (void)out_size;
    const float* x1 = (const float*)d_in[0];
    const float* x2 = (const float*)d_in[1];
    const float* w1 = (const float*)d_in[2];
    const float* w2 = (const float*)d_in[3];
    const float* w3 = (const float*)d_in[4];
    float* out = (float*)d_out;

    char* ws = (char*)d_ws;
    constexpr size_t XHB = (size_t)16 * PLANE * 64 * 2;   // 18,874,368 B
    unsigned short* xh1 = (unsigned short*)(ws);
    unsigned short* xh2 = (unsigned short*)(ws + XHB);    // reused as vf (NHWC)
    unsigned short* kf  = (unsigned short*)(ws + 2 * XHB);
    unsigned short* qf  = (unsigned short*)(ws + 3 * XHB);
    unsigned short* wl  = (unsigned short*)(ws + 4 * XHB);            // 3*9*4096
    unsigned short* dynw = (unsigned short*)(ws + 4 * XHB + 221184);  // 16*9*4096
    float* sc = (float*)(ws + 4 * XHB + 221184 + 1179648);

    size_t base = 4 * XHB + 221184 + 1179648;
    int nseg = (ws_size >= base + 4 * (size_t)SC_F * 4) ? 4 : 1;

    nchw2nhwc_bf16<<<dim3(1536), dim3(256), 0, stream>>>(x1, xh1);
    nchw2nhwc_bf16<<<dim3(1536), dim3(256), 0, stream>>>(x2, xh2);
    wreorder<<<dim3(27), dim3(256), 0, stream>>>(w1, w2, w3, wl);

    conv_mfma<<<dim3(1152), dim3(256), 0, stream>>>(xh1, wl,            kf, 0, 0);
    conv_mfma<<<dim3(1152), dim3(256), 0, stream>>>(xh2, wl + 9 * 4096, qf, 0, 0);
    scores_kernel<<<dim3(144 * nseg), dim3(256), 0, stream>>>(kf, qf, sc, nseg);
    softmax_kernel<<<dim3(1024), dim3(64), 0, stream>>>(sc, dynw, nseg);
    conv_mfma<<<dim3(1152), dim3(256), 0, stream>>>(xh1, wl + 18 * 4096, xh2, 1, 0); // vf NHWC
    conv_mfma<<<dim3(1152), dim3(256), 0, stream>>>(xh2, dynw, out, 2, 1);           // dynamic conv
}

// Round 3
// 286.905 us; speedup vs baseline: 13.2907x; 1.0033x over previous
//
#include <hip/hip_runtime.h>

// B=16, C=64->64, H=W=96, 3x3 pad-1 convs + 9-tap dynamic conv from attention.
// All convs: bf16 MFMA implicit GEMM. Scores: bf16 MFMA batched GEMM over a
// class-major layout written directly by the conv epilogue.

typedef __attribute__((ext_vector_type(8))) short short8v;   // 8 bf16 = 4 VGPRs
typedef __attribute__((ext_vector_type(4))) float floatx4;
typedef __attribute__((ext_vector_type(4))) unsigned int uint4v;

constexpr int PLANE = 9216;              // 96*96
constexpr int SCP_STRIDE = 589824;       // 16*9*4096 floats per K-segment

__device__ __forceinline__ unsigned short f2bf(float f) {
    unsigned int u = __float_as_uint(f);
    u = (u + 0x7FFFu + ((u >> 16) & 1u)) >> 16;
    return (unsigned short)u;
}

// ---------- fp32 NCHW -> bf16 NHWC (channels contiguous per pixel) ----------
__global__ __launch_bounds__(256) void nchw2nhwc_bf16(
    const float* __restrict__ x, unsigned short* __restrict__ xh)
{
    int blk = blockIdx.x;
    int b = blk / 96, y = blk - b * 96;
    __shared__ float ls[64][96];
    const float* xp = x + (size_t)b * 64 * PLANE + (size_t)y * 96;
    for (int i = threadIdx.x; i < 64 * 96; i += 256) {
        int ci = i / 96, xc = i - ci * 96;
        ls[ci][xc] = xp[(size_t)ci * PLANE + xc];
    }
    __syncthreads();
    unsigned short* op = xh + ((size_t)b * PLANE + (size_t)y * 96) * 64;
    for (int i = threadIdx.x; i < 96 * 8; i += 256) {
        int xc = i >> 3, cg = i & 7;
        unsigned short tmp[8] __attribute__((aligned(16)));
        #pragma unroll
        for (int j = 0; j < 8; ++j) tmp[j] = f2bf(ls[cg * 8 + j][xc]);
        *(uint4v*)&op[(size_t)xc * 64 + cg * 8] = *(const uint4v*)tmp;
    }
}

// ---------- weights [co][ci][kh][kw] fp32 -> [tap][co][ci] bf16 -------------
__global__ __launch_bounds__(256) void wreorder(
    const float* __restrict__ w1, const float* __restrict__ w2,
    const float* __restrict__ w3, unsigned short* __restrict__ wl)
{
    int blk = blockIdx.x;
    int wi = blk / 9, k9 = blk - wi * 9;
    const float* w = (wi == 0) ? w1 : ((wi == 1) ? w2 : w3);
    unsigned short* o = wl + (size_t)wi * 9 * 4096 + (size_t)k9 * 4096;
    for (int i = threadIdx.x; i < 4096; i += 256)   // i = co*64+ci
        o[i] = f2bf(w[(size_t)i * 9 + k9]);
}

// ---------- MFMA conv v2: 64 co x 256 px (8 rows x 32 cols) per block -------
// 4 waves: w&1 = co half (32 co = 2 m-tiles), w>>1 = row half (4 rows = 128 px).
// Per (tap, ci-half) step: 2 A global loads + 8 B ds_read_b128 -> 16 MFMA.
// omode: 1 = bf16 NHWC out, 2 = fp32 NCHW out, 3 = bf16 class-major [b][k][co][1024]
__global__ __launch_bounds__(256) void conv_mfma(
    const unsigned short* __restrict__ xh,   // [B][96][96][64] bf16
    const unsigned short* __restrict__ wl,   // [(b)][9][64co][64ci] bf16
    void* __restrict__ out, int omode, int dynb)
{
    int blk = blockIdx.x;
    int xs3 = blk % 3; int t = blk / 3;
    int yq = t % 12;   int b = t / 12;
    int x0 = xs3 * 32, y0 = yq * 8;

    // 10 halo rows x 34 halo cols x 64 ci; 16B-group g stored at slot g^(pc&7)
    __shared__ __align__(16) unsigned short xs[10 * 34 * 64];

    const unsigned short* xb = xh + (size_t)b * PLANE * 64;
    for (int i = threadIdx.x; i < 2720; i += 256) {
        int g = i & 7, pix = i >> 3;
        int pr = pix / 34, pc = pix - pr * 34;
        int y = y0 - 1 + pr, x = x0 - 1 + pc;
        uint4v v = {0u, 0u, 0u, 0u};
        if ((unsigned)y < 96u && (unsigned)x < 96u)
            v = *(const uint4v*)&xb[((size_t)y * 96 + x) * 64 + g * 8];
        *(uint4v*)&xs[pix * 64 + (g ^ (pc & 7)) * 8] = v;
    }
    __syncthreads();

    int lane = threadIdx.x & 63;
    int w = threadIdx.x >> 6;
    int ln = lane & 15, quad = lane >> 4;
    int coh  = (w & 1) * 32;
    int rowh = (w >> 1) * 4;

    const unsigned short* wb = wl + (dynb ? (size_t)b * 9 * 4096 : 0);

    floatx4 acc[2][8];
    #pragma unroll
    for (int mi = 0; mi < 2; ++mi)
        #pragma unroll
        for (int nt = 0; nt < 8; ++nt) acc[mi][nt] = (floatx4){0.f, 0.f, 0.f, 0.f};

    #pragma unroll
    for (int k9 = 0; k9 < 9; ++k9) {
        int dy = k9 / 3, dx = k9 - dy * 3;
        #pragma unroll
        for (int ch = 0; ch < 2; ++ch) {
            short8v a0 = *(const short8v*)
                &wb[((size_t)k9 * 64 + coh + ln) * 64 + ch * 32 + quad * 8];
            short8v a1 = *(const short8v*)
                &wb[((size_t)k9 * 64 + coh + 16 + ln) * 64 + ch * 32 + quad * 8];
            int gb = ch * 4 + quad;
            #pragma unroll
            for (int nt = 0; nt < 8; ++nt) {
                int n = nt * 16 + ln;
                int r = rowh + (n >> 5) + dy;
                int c = (n & 31) + dx;
                short8v bf = *(const short8v*)
                    &xs[(r * 34 + c) * 64 + (gb ^ (c & 7)) * 8];
                acc[0][nt] = __builtin_amdgcn_mfma_f32_16x16x32_bf16(a0, bf, acc[0][nt], 0, 0, 0);
                acc[1][nt] = __builtin_amdgcn_mfma_f32_16x16x32_bf16(a1, bf, acc[1][nt], 0, 0, 0);
            }
        }
    }

    // C/D: col(pixel) = lane&15, row(co) = quad*4+reg
    #pragma unroll
    for (int nt = 0; nt < 8; ++nt) {
        int n = nt * 16 + ln;
        int y = y0 + rowh + (n >> 5), x = x0 + (n & 31);
        if (omode == 2) {
            float* o = (float*)out;
            #pragma unroll
            for (int mi = 0; mi < 2; ++mi)
                #pragma unroll
                for (int reg = 0; reg < 4; ++reg) {
                    int co = coh + mi * 16 + quad * 4 + reg;
                    o[((size_t)(b * 64 + co)) * PLANE + (size_t)y * 96 + x] = acc[mi][nt][reg];
                }
        } else if (omode == 1) {
            unsigned short* o = (unsigned short*)out;
            #pragma unroll
            for (int mi = 0; mi < 2; ++mi) {
                unsigned short tmp[4] __attribute__((aligned(8)));
                #pragma unroll
                for (int reg = 0; reg < 4; ++reg) tmp[reg] = f2bf(acc[mi][nt][reg]);
                *(uint2*)&o[((size_t)b * PLANE + (size_t)y * 96 + x) * 64 + coh + mi * 16 + quad * 4]
                    = *(const uint2*)tmp;
            }
        } else {   // omode 3: class-major [b][k9][co][1024]
            unsigned short* o = (unsigned short*)out;
            int k9 = (y % 3) * 3 + (x % 3);
            int l = (y / 3) * 32 + (x / 3);
            #pragma unroll
            for (int mi = 0; mi < 2; ++mi)
                #pragma unroll
                for (int reg = 0; reg < 4; ++reg) {
                    int co = coh + mi * 16 + quad * 4 + reg;
                    o[((size_t)(b * 9 + k9) * 64 + co) * 1024 + l] = f2bf(acc[mi][nt][reg]);
                }
        }
    }
}

// ---------- scores: per (b,tap) 64x64x1024 MFMA GEMM on class-major data ----
// grid = 144*nseg, 4 waves split K; LDS reduce; partial -> scp[seg][bk][d*64+c]
__global__ __launch_bounds__(256) void scores_mfma(
    const unsigned short* __restrict__ kfc, const unsigned short* __restrict__ qfc,
    float* __restrict__ scp, int nseg)
{
    int blk = blockIdx.x;
    int seg = blk % nseg;
    int bk  = blk / nseg;                    // b*9+k
    int lane = threadIdx.x & 63, w = threadIdx.x >> 6;
    int ln = lane & 15, quad = lane >> 4;
    const unsigned short* ka = kfc + (size_t)bk * 64 * 1024;
    const unsigned short* qa = qfc + (size_t)bk * 64 * 1024;

    int Kblk = 1024 / nseg;
    int Kw   = Kblk / 4;
    int nch  = Kw / 32;

    floatx4 acc[4][4];
    #pragma unroll
    for (int i = 0; i < 4; ++i)
        #pragma unroll
        for (int j = 0; j < 4; ++j) acc[i][j] = (floatx4){0.f, 0.f, 0.f, 0.f};

    for (int chk = 0; chk < nch; ++chk) {
        int l = seg * Kblk + w * Kw + chk * 32 + quad * 8;
        short8v a[4], bq[4];
        #pragma unroll
        for (int mi = 0; mi < 4; ++mi)
            a[mi] = *(const short8v*)&ka[(size_t)(mi * 16 + ln) * 1024 + l];
        #pragma unroll
        for (int ni = 0; ni < 4; ++ni)
            bq[ni] = *(const short8v*)&qa[(size_t)(ni * 16 + ln) * 1024 + l];
        #pragma unroll
        for (int mi = 0; mi < 4; ++mi)
            #pragma unroll
            for (int ni = 0; ni < 4; ++ni)
                acc[mi][ni] = __builtin_amdgcn_mfma_f32_16x16x32_bf16(a[mi], bq[ni], acc[mi][ni], 0, 0, 0);
    }

    __shared__ float ls[4][64][65];
    #pragma unroll
    for (int mi = 0; mi < 4; ++mi)
        #pragma unroll
        for (int ni = 0; ni < 4; ++ni)
            #pragma unroll
            for (int reg = 0; reg < 4; ++reg)
                ls[w][ni * 16 + ln][mi * 16 + quad * 4 + reg] = acc[mi][ni][reg];
    __syncthreads();

    float* op = scp + (size_t)seg * SCP_STRIDE + (size_t)bk * 4096;
    int t = threadIdx.x;
    #pragma unroll
    for (int j = 0; j < 16; ++j) {
        int e = t * 16 + j;
        int d = e >> 6, c = e & 63;
        op[e] = ls[0][d][c] + ls[1][d][c] + ls[2][d][c] + ls[3][d][c];
    }
}

// ---------- softmax over (c,k) per (b,d) -> dynamic weights bf16 ------------
// grid 256 blocks x 256 thr; 4 rows per block; lane = c.
__global__ __launch_bounds__(256) void softmax_kernel(
    const float* __restrict__ scp, unsigned short* __restrict__ dynw, int nseg)
{
    int w = threadIdx.x >> 6, c = threadIdx.x & 63;
    int row = blockIdx.x * 4 + w;          // b*64+d
    int b = row >> 6, d = row & 63;
    float v[9];
    float mx = -3.0e38f;
    #pragma unroll
    for (int k = 0; k < 9; ++k) {
        size_t idx = (size_t)(b * 9 + k) * 4096 + d * 64 + c;
        float s = scp[idx];
        for (int g = 1; g < nseg; ++g) s += scp[(size_t)g * SCP_STRIDE + idx];
        v[k] = s * (1.0f / 24.0f);         // 1/sqrt(576)
        mx = fmaxf(mx, v[k]);
    }
    #pragma unroll
    for (int o = 32; o; o >>= 1) mx = fmaxf(mx, __shfl_xor(mx, o));
    float sum = 0.f;
    #pragma unroll
    for (int k = 0; k < 9; ++k) { v[k] = __expf(v[k] - mx); sum += v[k]; }
    #pragma unroll
    for (int o = 32; o; o >>= 1) sum += __shfl_xor(sum, o);
    float inv = 1.0f / sum;
    #pragma unroll
    for (int k = 0; k < 9; ++k)
        dynw[((size_t)(b * 9 + k) * 64 + d) * 64 + c] = f2bf(v[k] * inv);
}

extern "C" void kernel_launch(void* const* d_in, const int* in_sizes, int n_in,
                              void* d_out, int out_size, void* d_ws, size_t ws_size,
                              hipStream_t stream) {
    (void)in_sizes; (void)n_in; (void)out_size;
    const float* x1 = (const float*)d_in[0];
    const float* x2 = (const float*)d_in[1];
    const float* w1 = (const float*)d_in[2];
    const float* w2 = (const float*)d_in[3];
    const float* w3 = (const float*)d_in[4];
    float* out = (float*)d_out;

    char* ws = (char*)d_ws;
    constexpr size_t XHB = (size_t)16 * PLANE * 64 * 2;     // 18,874,368 B
    unsigned short* xh1 = (unsigned short*)(ws);
    unsigned short* xh2 = (unsigned short*)(ws + XHB);      // reused as vf (NHWC)
    unsigned short* kfc = (unsigned short*)(ws + 2 * XHB);  // class-major
    unsigned short* qfc = (unsigned short*)(ws + 3 * XHB);
    unsigned short* wl  = (unsigned short*)(ws + 4 * XHB);              // 221,184 B
    unsigned short* dynw = (unsigned short*)(ws + 4 * XHB + 221184);    // 1,179,648 B
    float* scp = (float*)(ws + 4 * XHB + 221184 + 1179648);

    size_t base = 4 * XHB + 221184 + 1179648;
    int nseg = (ws_size >= base + 2 * (size_t)SCP_STRIDE * 4) ? 2 : 1;

    nchw2nhwc_bf16<<<dim3(1536), dim3(256), 0, stream>>>(x1, xh1);
    nchw2nhwc_bf16<<<dim3(1536), dim3(256), 0, stream>>>(x2, xh2);
    wreorder<<<dim3(27), dim3(256), 0, stream>>>(w1, w2, w3, wl);

    conv_mfma<<<dim3(576), dim3(256), 0, stream>>>(xh1, wl,            kfc, 3, 0);
    conv_mfma<<<dim3(576), dim3(256), 0, stream>>>(xh2, wl + 9 * 4096, qfc, 3, 0);
    scores_mfma<<<dim3(144 * nseg), dim3(256), 0, stream>>>(kfc, qfc, scp, nseg);
    softmax_kernel<<<dim3(256), dim3(256), 0, stream>>>(scp, dynw, nseg);
    conv_mfma<<<dim3(576), dim3(256), 0, stream>>>(xh1, wl + 18 * 4096, xh2, 1, 0); // vf NHWC
    conv_mfma<<<dim3(576), dim3(256), 0, stream>>>(xh2, dynw, out, 2, 1);           // dynamic conv
}